// Round 10
// baseline (28563.815 us; speedup 1.0000x reference)
//
#include <hip/hip_runtime.h>
#include <hip/hip_bf16.h>

#define B_   64
#define T_   512
#define E_   300
#define U_   512
#define G4_  2048
#define D1_  1024
#define D2_  1024
#define NC_  20
#define KP_  320          // E_ padded to multiple of 32 for MFMA

typedef __bf16 bf16x8 __attribute__((ext_vector_type(8)));
typedef float  f32x4  __attribute__((ext_vector_type(4)));

__device__ __forceinline__ float sigmoidf_(float x) { return 1.0f / (1.0f + __expf(-x)); }

__device__ __forceinline__ void gl_lds16(const void* g, void* l) {
    __builtin_amdgcn_global_load_lds(
        (const __attribute__((address_space(1))) unsigned int*)g,
        (__attribute__((address_space(3))) unsigned int*)l, 16, 0, 0);
}

// ---------------------------------------------------------------------------
// prep: Wx (300x2048 f32) -> WxT[2048][320] bf16 (transposed, K zero-padded)
// ---------------------------------------------------------------------------
__global__ __launch_bounds__(256) void prep_wxT(const float* __restrict__ Wx,
                                                __hip_bfloat16* __restrict__ wxT) {
    __shared__ __hip_bfloat16 t[64][65];
    const int n0 = blockIdx.x * 64;   // 32 tiles
    const int k0 = blockIdx.y * 64;   // 5 tiles
    const int tid = threadIdx.x;
    for (int i = tid; i < 4096; i += 256) {
        int r = i >> 6, c = i & 63;                 // r = k-local, c = n-local
        int k = k0 + r;
        float v = (k < E_) ? Wx[(size_t)k * G4_ + n0 + c] : 0.f;
        t[r][c] = __float2bfloat16(v);
    }
    __syncthreads();
    for (int i = tid; i < 4096; i += 256) {
        int r = i >> 6, c = i & 63;                 // r = n-local, c = k-local
        wxT[(size_t)(n0 + r) * KP_ + k0 + c] = t[c][r];
    }
}

// ---------------------------------------------------------------------------
// prep: gather + cvt  xb[bt][k] = bf16(emb[tokens[bt]][k]), zero-padded K
// ---------------------------------------------------------------------------
__global__ __launch_bounds__(256) void prep_xb(const int* __restrict__ tokens,
                                               const float* __restrict__ emb,
                                               __hip_bfloat16* __restrict__ xb) {
    const int row = blockIdx.x * 4 + (threadIdx.x >> 6);
    const int ln  = threadIdx.x & 63;
    const int tok = tokens[row];
    const float* src = emb + (size_t)tok * E_;
    __hip_bfloat16* dst = xb + (size_t)row * KP_;
    for (int k = ln; k < KP_; k += 64)
        dst[k] = (k < E_) ? __float2bfloat16(src[k]) : __float2bfloat16(0.f);
}

// ---------------------------------------------------------------------------
// xg GEMM (MFMA): xg[t][b][n] = xb[bt] @ WxT^T + bias   (m97-style 128x128)
// ---------------------------------------------------------------------------
__global__ __launch_bounds__(256) void xg_gemm(const __hip_bfloat16* __restrict__ xb,
                                               const __hip_bfloat16* __restrict__ wxT,
                                               const float* __restrict__ bias,
                                               __hip_bfloat16* __restrict__ xg) {
    const int n0g = blockIdx.x * 128;   // 16
    const int bt0 = blockIdx.y * 128;   // 256
    const int tid = threadIdx.x;
    const int w   = tid >> 6;
    const int ln  = tid & 63;
    const int fn  = ln & 15;
    const int quad = ln >> 4;
    const int m0  = (w >> 1) * 64;
    const int n0w = (w & 1) * 64;

    __shared__ __align__(16) __hip_bfloat16 As[128 * 32];
    __shared__ __align__(16) __hip_bfloat16 Bs[128 * 32];

    f32x4 acc[4][4];
    #pragma unroll
    for (int im = 0; im < 4; ++im)
        #pragma unroll
        for (int in = 0; in < 4; ++in)
            acc[im][in] = (f32x4){0.f, 0.f, 0.f, 0.f};

    const __hip_bfloat16* ga = xb  + (size_t)(bt0 + w * 32 + (ln >> 2)) * KP_ + (ln & 3) * 8;
    const __hip_bfloat16* gb = wxT + (size_t)(n0g + w * 32 + (ln >> 2)) * KP_ + (ln & 3) * 8;

    for (int kt = 0; kt < KP_ / 32; ++kt) {
        gl_lds16(ga,             &As[(w * 32) * 32]);
        gl_lds16(ga + 16 * KP_,  &As[(w * 32 + 16) * 32]);
        gl_lds16(gb,             &Bs[(w * 32) * 32]);
        gl_lds16(gb + 16 * KP_,  &Bs[(w * 32 + 16) * 32]);
        ga += 32; gb += 32;
        __syncthreads();

        bf16x8 af[4], bf[4];
        #pragma unroll
        for (int im = 0; im < 4; ++im)
            af[im] = *(const bf16x8*)&As[(m0 + im * 16 + fn) * 32 + quad * 8];
        #pragma unroll
        for (int in = 0; in < 4; ++in)
            bf[in] = *(const bf16x8*)&Bs[(n0w + in * 16 + fn) * 32 + quad * 8];
        #pragma unroll
        for (int im = 0; im < 4; ++im)
            #pragma unroll
            for (int in = 0; in < 4; ++in)
                acc[im][in] = __builtin_amdgcn_mfma_f32_16x16x32_bf16(
                    af[im], bf[in], acc[im][in], 0, 0, 0);
        __syncthreads();
    }

    #pragma unroll
    for (int in = 0; in < 4; ++in) {
        const int n = n0g + n0w + in * 16 + fn;
        const float bv = bias[n];
        #pragma unroll
        for (int im = 0; im < 4; ++im) {
            #pragma unroll
            for (int r = 0; r < 4; ++r) {
                int m = bt0 + m0 + im * 16 + quad * 4 + r;   // bt = b*T + t
                int bb = m >> 9, tt = m & 511;
                xg[(size_t)(tt * B_ + bb) * G4_ + n] =
                    __float2bfloat16(acc[im][in][r] + bv);
            }
        }
    }
}

// ---------------------------------------------------------------------------
// prep: Wh (512x2048 f32) -> Whp packed MFMA B-fragments, bf16.
// Whp[((t*16 + kk)*64 + lane)*8 + j] = Wh[kk*32 + (lane>>4)*8 + j][t*16 + (lane&15)]
// so the lstm kernel's B-operand loads are coalesced dwordx4 (tile t = col/16,
// kk = k/32). Size: 128*16*64*16 B = 2 MB (L2-resident per XCD).
// ---------------------------------------------------------------------------
__global__ __launch_bounds__(256) void prep_whp(const float* __restrict__ Wh,
                                                __hip_bfloat16* __restrict__ whp) {
    __shared__ __hip_bfloat16 t64[64][72];
    const int c0 = blockIdx.x * 64;   // 32
    const int k0 = blockIdx.y * 64;   // 8
    const int tid = threadIdx.x;
    for (int i = tid; i < 4096; i += 256) {
        int r = i >> 6, c = i & 63;
        t64[r][c] = __float2bfloat16(Wh[(size_t)(k0 + r) * G4_ + c0 + c]);
    }
    __syncthreads();
    #pragma unroll
    for (int q = 0; q < 2; ++q) {
        int fi  = tid + q * 256;            // 0..511 fragments of this 64x64 tile
        int tc  = fi >> 7;                  // 0..3 col-subtile
        int kk2 = (fi >> 6) & 1;            // 0..1 k-subtile
        int l   = fi & 63;
        int fn  = l & 15, qd = l >> 4;
        int tg  = (c0 >> 4) + tc;
        int kkg = (k0 >> 5) + kk2;
        __hip_bfloat16 frag[8];
        #pragma unroll
        for (int j = 0; j < 8; ++j)
            frag[j] = t64[kk2 * 32 + qd * 8 + j][tc * 16 + fn];
        uint4 v;
        __builtin_memcpy(&v, frag, 16);
        *(uint4*)(whp + ((size_t)(tg * 16 + kkg) * 64 + l) * 8) = v;
    }
}

// ---------------------------------------------------------------------------
// LSTM round-10: EXCHANGE-FREE. 4 blocks x 512 threads; block g owns batches
// g*16..g*16+15 and ALL 512 units -> the recurrence is block-internal (h in
// LDS, cell state in registers). No flags, no sc0/sc1, no coherence RTs —
// the R0-R9 ~5500cy/step floor was 3 device-scope round trips/step; here the
// step is MFMA-pipe-bound (~2500cy: 2048 MFMA / 4 SIMDs).
// Wh streamed from L2 each step via Whp packed fragments (2 MB, L2-hot).
// xg staged to LDS one step ahead (global_load_lds), hidden under MFMA.
// Wave w owns units w*64..+63 (4 chunks x 16); lane owns (unit, 4 batches).
// MFMA fragment pattern verbatim from the R0-verified kernel.
// LDS: hs 2x16x520x2 = 33.3KB + xs 64KB + mask 1KB = 98.3KB.
// ---------------------------------------------------------------------------
__global__ __launch_bounds__(512) void lstm_kernel(const __hip_bfloat16* __restrict__ xg,
                                                   const int* __restrict__ tokens,
                                                   const __hip_bfloat16* __restrict__ whp,
                                                   __hip_bfloat16* __restrict__ hout) {
    const int tid  = threadIdx.x;
    const int w    = tid >> 6;
    const int lane = tid & 63;
    const int fn   = lane & 15;
    const int quad = lane >> 4;
    const int g    = blockIdx.x;

    __shared__ __align__(16) __hip_bfloat16 hsbuf[2][16][520];
    __shared__ __align__(16) __hip_bfloat16 xs[16 * 2048];
    __shared__ unsigned mask_lds[16][16];

    // zero hs (both parities; padding harmless)
    {
        __hip_bfloat16* hz = &hsbuf[0][0][0];
        for (int i = tid; i < 2 * 16 * 520; i += 512) hz[i] = __float2bfloat16(0.f);
    }
    // token!=0 bitmask for this block's 16 batches
    if (tid < 256) {
        int m = tid >> 4, wi = tid & 15;
        const int4* tp = (const int4*)(tokens + (size_t)(g * 16 + m) * T_ + wi * 32);
        unsigned bits = 0;
        #pragma unroll
        for (int q = 0; q < 8; ++q) {
            int4 v = tp[q];
            bits |= (v.x != 0 ? 1u : 0u) << (q * 4 + 0);
            bits |= (v.y != 0 ? 1u : 0u) << (q * 4 + 1);
            bits |= (v.z != 0 ? 1u : 0u) << (q * 4 + 2);
            bits |= (v.w != 0 ? 1u : 0u) << (q * 4 + 3);
        }
        mask_lds[m][wi] = bits;
    }

    // per-lane cell state: chunk c (unit = w*64+c*16+fn), batch quad*4+r
    float cst[4][4], hst[4][4];
    #pragma unroll
    for (int c = 0; c < 4; ++c)
        #pragma unroll
        for (int r = 0; r < 4; ++r) { cst[c][r] = 0.f; hst[c][r] = 0.f; }

    // stage xs for s=0: 16 rows x 2048 bf16 = 64KB, wave w stages bytes [w*8K, w*8K+8K)
    {
        const char* src = (const char*)(xg + ((size_t)0 * B_ + g * 16) * G4_) +
                          (w << 13) + (lane << 4);
        char* dst = (char*)xs + (w << 13);
        #pragma unroll
        for (int i = 0; i < 8; ++i)
            gl_lds16(src + (i << 10), dst + (i << 10));
    }
    __syncthreads();   // hs zero + mask + xs(0) all ready (implicit vmcnt drain)

    const bf16x8* bbase = (const bf16x8*)whp + lane;

    for (int s = 0; s < T_; ++s) {
        const int par = s & 1;

        // ---- MFMA phase: 16 units x 4 gates x 4 chunks per wave ----
        f32x4 acc[4][4];   // [chunk][gate]
        #pragma unroll
        for (int c = 0; c < 4; ++c)
            #pragma unroll
            for (int gt = 0; gt < 4; ++gt)
                acc[c][gt] = (f32x4){0.f, 0.f, 0.f, 0.f};

        const __hip_bfloat16* hrow = &hsbuf[par][fn][quad * 8];
        #pragma unroll
        for (int kk = 0; kk < 16; ++kk) {
            bf16x8 av = *(const bf16x8*)(hrow + kk * 32);
            #pragma unroll
            for (int c = 0; c < 4; ++c) {
                #pragma unroll
                for (int gt = 0; gt < 4; ++gt) {
                    const int t = gt * 32 + (w << 2) + c;      // col tile
                    bf16x8 bv = bbase[(size_t)t * 1024 + kk * 64];
                    acc[c][gt] = __builtin_amdgcn_mfma_f32_16x16x32_bf16(
                        av, bv, acc[c][gt], 0, 0, 0);
                }
            }
        }
        __syncthreads();   // xs(s) staged+drained; MFMA hs reads done

        // ---- elementwise (in-register state), write h(s+1) to LDS ----
        #pragma unroll
        for (int c = 0; c < 4; ++c) {
            const int u = (w << 6) + (c << 4) + fn;
            #pragma unroll
            for (int r = 0; r < 4; ++r) {
                const int m = (quad << 2) + r;
                const __hip_bfloat16* xr = &xs[m * 2048];
                float xi = __bfloat162float(xr[u]);
                float xf = __bfloat162float(xr[512 + u]);
                float xc = __bfloat162float(xr[1024 + u]);
                float xo = __bfloat162float(xr[1536 + u]);
                float gi = sigmoidf_(acc[c][0][r] + xi);
                float gf = sigmoidf_(acc[c][1][r] + xf);
                float gc = acc[c][2][r] + xc;
                float go = sigmoidf_(acc[c][3][r] + xo);
                float cn = gf * cst[c][r] + gi * fmaxf(gc, 0.f);
                float hn = go * fmaxf(cn, 0.f);
                if ((mask_lds[m][s >> 5] >> (s & 31)) & 1u) {
                    cst[c][r] = cn; hst[c][r] = hn;
                }
                hsbuf[par ^ 1][m][u] = __float2bfloat16(hst[c][r]);
            }
        }
        __syncthreads();   // h(s+1) visible; xs(s) reads complete

        // ---- stage xs for s+1 (hides under next MFMA phase) ----
        if (s + 1 < T_) {
            const char* src = (const char*)(xg + ((size_t)(s + 1) * B_ + g * 16) * G4_) +
                              (w << 13) + (lane << 4);
            char* dst = (char*)xs + (w << 13);
            #pragma unroll
            for (int i = 0; i < 8; ++i)
                gl_lds16(src + (i << 10), dst + (i << 10));
        }
    }

    // ---- write final h (parity 0 after T=512 steps) to global ----
    for (int i = tid; i < 16 * 512; i += 512) {
        int m = i >> 9, uu = i & 511;
        hout[(size_t)(g * 16 + m) * U_ + uu] = hsbuf[0][m][uu];
    }
}

// ---------------------------------------------------------------------------
// FC layers
// ---------------------------------------------------------------------------
__global__ __launch_bounds__(256) void fc1_kernel(const __hip_bfloat16* __restrict__ h,
                                                  const float* __restrict__ W,
                                                  const float* __restrict__ bias,
                                                  float* __restrict__ y) {
    int b = blockIdx.x >> 2, ch = blockIdx.x & 3;
    __shared__ float xrow[U_];
    for (int i = threadIdx.x; i < U_; i += 256)
        xrow[i] = __bfloat162float(h[b * U_ + i]);
    __syncthreads();
    int n = ch * 256 + threadIdx.x;
    float acc = 0.f;
    #pragma unroll 4
    for (int k = 0; k < U_; ++k) acc = fmaf(xrow[k], W[(size_t)k * D1_ + n], acc);
    y[b * D1_ + n] = fmaxf(acc + bias[n], 0.f);
}

__global__ __launch_bounds__(256) void fc2_kernel(const float* __restrict__ x,
                                                  const float* __restrict__ W,
                                                  const float* __restrict__ bias,
                                                  float* __restrict__ y) {
    int b = blockIdx.x >> 2, ch = blockIdx.x & 3;
    __shared__ float xrow[D1_];
    for (int i = threadIdx.x; i < D1_; i += 256) xrow[i] = x[b * D1_ + i];
    __syncthreads();
    int n = ch * 256 + threadIdx.x;
    float acc = 0.f;
    #pragma unroll 4
    for (int k = 0; k < D1_; ++k) acc = fmaf(xrow[k], W[(size_t)k * D2_ + n], acc);
    y[b * D2_ + n] = fmaxf(acc + bias[n], 0.f);
}

// ---------------------------------------------------------------------------
// logits + softmax
// ---------------------------------------------------------------------------
__global__ __launch_bounds__(64) void out_kernel(const float* __restrict__ h2,
                                                 const float* __restrict__ Wo,
                                                 const float* __restrict__ bo,
                                                 float* __restrict__ out) {
    int b = blockIdx.x;
    __shared__ float xrow[D2_];
    __shared__ float lg[NC_];
    __shared__ float red[2];
    for (int i = threadIdx.x; i < D2_; i += 64) xrow[i] = h2[b * D2_ + i];
    __syncthreads();
    if (threadIdx.x < NC_) {
        float a = bo[threadIdx.x];
        for (int k = 0; k < D2_; ++k) a = fmaf(xrow[k], Wo[k * NC_ + threadIdx.x], a);
        lg[threadIdx.x] = a;
    }
    __syncthreads();
    if (threadIdx.x == 0) {
        float mx = lg[0];
        for (int c = 1; c < NC_; ++c) mx = fmaxf(mx, lg[c]);
        float sm = 0.f;
        for (int c = 0; c < NC_; ++c) sm += expf(lg[c] - mx);
        red[0] = mx; red[1] = 1.0f / sm;
    }
    __syncthreads();
    if (threadIdx.x < NC_)
        out[b * NC_ + threadIdx.x] = expf(lg[threadIdx.x] - red[0]) * red[1];
}

// ---------------------------------------------------------------------------
extern "C" void kernel_launch(void* const* d_in, const int* in_sizes, int n_in,
                              void* d_out, int out_size, void* d_ws, size_t ws_size,
                              hipStream_t stream) {
    const int*   tokens = (const int*)d_in[0];
    const float* emb    = (const float*)d_in[1];
    const float* Wx     = (const float*)d_in[2];
    const float* Wh     = (const float*)d_in[3];
    const float* b      = (const float*)d_in[4];
    const float* W1     = (const float*)d_in[5];
    const float* b1     = (const float*)d_in[6];
    const float* W2     = (const float*)d_in[7];
    const float* b2     = (const float*)d_in[8];
    const float* Wo     = (const float*)d_in[9];
    const float* bo     = (const float*)d_in[10];
    float* out = (float*)d_out;

    char* ws = (char*)d_ws;
    const size_t XG_BYTES   = (size_t)T_ * B_ * G4_ * 2;        // 134,217,728
    const size_t HBUF_BYTES = (size_t)B_ * U_ * 2;              // 65,536
    const size_t WHP_BYTES  = (size_t)128 * 16 * 64 * 16;       // 2,097,152
    __hip_bfloat16* xg   = (__hip_bfloat16*)ws;
    __hip_bfloat16* hbuf = (__hip_bfloat16*)(ws + XG_BYTES);
    __hip_bfloat16* whp  = (__hip_bfloat16*)(ws + XG_BYTES + HBUF_BYTES);
    char* p = ws + XG_BYTES + HBUF_BYTES + WHP_BYTES;
    float* h1            = (float*)p;                 p += (size_t)B_ * D1_ * 4;
    float* h2            = (float*)p;                 p += (size_t)B_ * D2_ * 4;
    __hip_bfloat16* xb   = (__hip_bfloat16*)p;        p += (size_t)B_ * T_ * KP_ * 2;
    __hip_bfloat16* wxT  = (__hip_bfloat16*)p;        // 2048*320*2 = 1.3 MB

    prep_wxT<<<dim3(32, 5), 256, 0, stream>>>(Wx, wxT);
    prep_xb<<<(B_ * T_) / 4, 256, 0, stream>>>(tokens, emb, xb);
    xg_gemm<<<dim3(16, 256), 256, 0, stream>>>(xb, wxT, b, xg);
    prep_whp<<<dim3(32, 8), 256, 0, stream>>>(Wh, whp);
    lstm_kernel<<<4, 512, 0, stream>>>(xg, tokens, whp, hbuf);
    fc1_kernel<<<256, 256, 0, stream>>>(hbuf, W1, b1, h1);
    fc2_kernel<<<256, 256, 0, stream>>>(h1, W2, b2, h2);
    out_kernel<<<64, 64, 0, stream>>>(h2, Wo, bo, out);
}